// Round 9
// baseline (217.518 us; speedup 1.0000x reference)
//
#include <hip/hip_runtime.h>

// ---------------------------------------------------------------------------
// MultiHeadAttention: x(4,2048,512) fp32, adj(4,2048,2048) 0/1 fp32
// R20: 3-dispatch pipeline, done right this time (R18's regression = scalar
// abits tail; both fixed). Accounting R18<->R19 shows >=59us of per-dispatch
// overhead -> dispatch count is first-order.
//  - prep_k DELETED. gemm0 stages A=x f32 + B=wqkv f32 via v_cvt_pk_bf16_f32
//    (kills x_bf 16MB write + 8MB read); gemm1 stages B=outw f32 likewise.
//  - adj bit-pack = blocks 0..511 of the gemm0 launch (FIRST, co-resident
//    with gemm blocks; float4 + 4-ballot form from R19, ~11us overlapped).
//  - abits layout ballot-natural [b][it(8)][q][4] (R19), attn decode matching.
// Pipeline: [abits|gemm0](1280) -> attn(512) -> gemm1(256).
// attn_k identical to R19 (49.7us, 0 bank conflicts).
// ---------------------------------------------------------------------------

typedef __attribute__((ext_vector_type(8))) short bf16x8;
typedef __attribute__((ext_vector_type(4))) float f32x4;
typedef __attribute__((ext_vector_type(4))) unsigned short ushort4v;
typedef __attribute__((ext_vector_type(4))) _Float16 f16x4;
typedef __attribute__((ext_vector_type(8))) _Float16 f16x8;
typedef __attribute__((ext_vector_type(2))) __fp16 h16x2;  // cvt_pkrtz return type
typedef __attribute__((ext_vector_type(2))) unsigned long long u64x2;

#if __has_builtin(__builtin_amdgcn_exp2f)
#define EXP2F(x) __builtin_amdgcn_exp2f(x)
#else
#define EXP2F(x) exp2f(x)
#endif

// 0.125 (1/sqrt(64)) * log2(e), folded into Q at the QKV-gemm epilogue
#define QSCALE 0.18033688011112042f

__device__ __forceinline__ unsigned short f2bf(float f) {
  unsigned int u = __float_as_uint(f);
  u += 0x7FFFu + ((u >> 16) & 1u);
  return (unsigned short)(u >> 16);
}
__device__ __forceinline__ unsigned short f2h(float f) {
  union { _Float16 h; unsigned short u; } cv;
  cv.h = (_Float16)f;
  return cv.u;
}

// packed f32x2 -> bf16x2 (RNE), gfx950 inline asm (no builtin)
__device__ __forceinline__ unsigned cvtpk_bf16(float a, float b) {
  unsigned r;
  asm("v_cvt_pk_bf16_f32 %0, %1, %2" : "=v"(r) : "v"(a), "v"(b));
  return r;
}
// 8 floats (two float4) -> bf16x8 via 4 packed converts
__device__ __forceinline__ bf16x8 cvt8(float4 lo, float4 hi) {
  union { unsigned u[4]; bf16x8 v; } r;
  r.u[0] = cvtpk_bf16(lo.x, lo.y);
  r.u[1] = cvtpk_bf16(lo.z, lo.w);
  r.u[2] = cvtpk_bf16(hi.x, hi.y);
  r.u[3] = cvtpk_bf16(hi.z, hi.w);
  return r.v;
}

// sign-extend bit (pos) of w to 0 / 0xFFFFFFFF
__device__ __forceinline__ int sbit(unsigned w, int pos) {
  return ((int)(w << (31 - pos))) >> 31;  // compiler emits v_bfe_i32
}

// pack 8 floats -> f16x8 via 4 packed RTZ converts
__device__ __forceinline__ f16x8 pk8(const float* p) {
  union { struct { h16x2 a, b, c, d; } s; f16x8 v; } u;
  u.s.a = __builtin_amdgcn_cvt_pkrtz(p[0], p[1]);
  u.s.b = __builtin_amdgcn_cvt_pkrtz(p[2], p[3]);
  u.s.c = __builtin_amdgcn_cvt_pkrtz(p[4], p[5]);
  u.s.d = __builtin_amdgcn_cvt_pkrtz(p[6], p[7]);
  return u.v;
}

// PV matmul: K=32 f16 (slot pairing identical in A and B, so a two-K=16
// fallback is mathematically identical if the builtin is absent)
__device__ __forceinline__ f32x4 mfma_pv(f16x8 a, f16x8 b, f32x4 c) {
#if __has_builtin(__builtin_amdgcn_mfma_f32_16x16x32_f16)
  return __builtin_amdgcn_mfma_f32_16x16x32_f16(a, b, c, 0, 0, 0);
#else
  union { f16x8 v; struct { f16x4 lo, hi; } s; } ua, ub;
  ua.v = a; ub.v = b;
  c = __builtin_amdgcn_mfma_f32_16x16x16f16(ua.s.lo, ub.s.lo, c, 0, 0, 0);
  return __builtin_amdgcn_mfma_f32_16x16x16f16(ua.s.hi, ub.s.hi, c, 0, 0, 0);
#endif
}

// ---------------- 128x128 bf16 MFMA GEMM: C = A @ Bt^T (+bias) ----------------
// Staging converts f32 sources to bf16 in-flight (v_cvt_pk_bf16_f32).
// MODE 0: blocks [0,512) = adj->abits bit-pack (float4 + 4 ballots, runs
//         FIRST, co-resident with gemm blocks); blocks [512,1280) = QKV gemm
//         (A = x f32, B = wqkv f32). Epilogue: Q scaled bf16 / K bf16 /
//         V f16 LDS-transposed.
// MODE 1: A = Ob bf16, B = outw f32; fp32 + bias epilogue to f_out.
// XCD-local mt grouping: gblk&7 = XCD (both mode grids are multiples of 8).
template <int MODE>
__global__ __launch_bounds__(256, 3) void gemm128_k(const float* __restrict__ Af,
                                                    const unsigned short* __restrict__ Abf,
                                                    const float* __restrict__ Btf,
                                                    const float* __restrict__ bias, int Ntiles,
                                                    unsigned short* __restrict__ q_out,
                                                    unsigned short* __restrict__ k_out,
                                                    unsigned short* __restrict__ v_out,
                                                    float* __restrict__ f_out,
                                                    const float* __restrict__ adj,
                                                    unsigned long long* __restrict__ abits) {
  __shared__ union {
    struct { unsigned short A[2][128][40], B[2][128][40]; } s;  // 40 KB
    unsigned short T[64][136];                                  // V-transpose staging
  } u;

  const int t = threadIdx.x;

  if (MODE == 0 && blockIdx.x < 512) {
    // adj -> ballot-natural masks: [b][it(8)][q][4]; W_c bit l = adj[q][256it+4l+c]
    const int w = t >> 6, l = t & 63;
    const int base = blockIdx.x * 16;
#pragma unroll
    for (int i = 0; i < 4; ++i) {
      const int gw = base + w * 4 + i;  // 0..8191 = b*2048+q
      const int b = gw >> 11, q = gw & 2047;
      const float4* row = (const float4*)(adj + ((size_t)b * 2048 + q) * 2048) + l;
      unsigned long long* ob = abits + ((size_t)b * 8 * 2048 + q) * 4;
#pragma unroll
      for (int it = 0; it < 8; ++it) {
        const float4 v = row[(size_t)it * 64];
        const unsigned long long w0 = __ballot(v.x != 0.f);
        const unsigned long long w1 = __ballot(v.y != 0.f);
        const unsigned long long w2 = __ballot(v.z != 0.f);
        const unsigned long long w3 = __ballot(v.w != 0.f);
        if (l == 0) {
          ob[(size_t)it * 8192 + 0] = w0;
          ob[(size_t)it * 8192 + 1] = w1;
          ob[(size_t)it * 8192 + 2] = w2;
          ob[(size_t)it * 8192 + 3] = w3;
        }
      }
    }
    return;
  }

  const int gblk = (MODE == 0) ? (blockIdx.x - 512) : blockIdx.x;
  const int lane = t & 63, w = t >> 6, ln = lane & 15, quad = lane >> 4;
  // XCD-local mt grouping; mt-groups-per-xcd = 8 for both modes (768/8/12, 256/8/4)
  const int xcd = gblk & 7, loc = gblk >> 3;
  const int mt = xcd * 8 + loc / Ntiles;
  const int nt = loc % Ntiles;
  const int wm = (w >> 1) * 64, wn = (w & 1) * 64;
  const int strow = t >> 2, stcol = (t & 3) * 8;

  const size_t abase = (size_t)(mt * 128 + strow) * 512 + stcol;
  const size_t bbase = (size_t)(nt * 128 + strow) * 512 + stcol;

  f32x4 acc[4][4];
#pragma unroll
  for (int i = 0; i < 4; ++i)
#pragma unroll
    for (int j = 0; j < 4; ++j) acc[i][j] = (f32x4){0.f, 0.f, 0.f, 0.f};

  // staging load helper: A from f32 (MODE0) or bf16 (MODE1); B always f32
  bf16x8 a0, a1, b0, b1;
#define LOADAB(kn)                                                              \
  {                                                                             \
    if (MODE == 0) {                                                            \
      float4 l0 = *(const float4*)(Af + abase + (kn));                          \
      float4 h0 = *(const float4*)(Af + abase + (kn) + 4);                      \
      float4 l1 = *(const float4*)(Af + abase + (size_t)64 * 512 + (kn));       \
      float4 h1 = *(const float4*)(Af + abase + (size_t)64 * 512 + (kn) + 4);   \
      a0 = cvt8(l0, h0);                                                        \
      a1 = cvt8(l1, h1);                                                        \
    } else {                                                                    \
      a0 = *(const bf16x8*)(Abf + abase + (kn));                                \
      a1 = *(const bf16x8*)(Abf + abase + (size_t)64 * 512 + (kn));             \
    }                                                                           \
    float4 bl0 = *(const float4*)(Btf + bbase + (kn));                          \
    float4 bh0 = *(const float4*)(Btf + bbase + (kn) + 4);                      \
    float4 bl1 = *(const float4*)(Btf + bbase + (size_t)64 * 512 + (kn));       \
    float4 bh1 = *(const float4*)(Btf + bbase + (size_t)64 * 512 + (kn) + 4);   \
    b0 = cvt8(bl0, bh0);                                                        \
    b1 = cvt8(bl1, bh1);                                                        \
  }

  // prologue: load + stage chunk 0 into buf 0
  LOADAB(0);
  *(bf16x8*)&u.s.A[0][strow][stcol] = a0;
  *(bf16x8*)&u.s.A[0][64 + strow][stcol] = a1;
  *(bf16x8*)&u.s.B[0][strow][stcol] = b0;
  *(bf16x8*)&u.s.B[0][64 + strow][stcol] = b1;
  __syncthreads();

  for (int it = 0; it < 16; ++it) {
    const int cur = it & 1, nxt = cur ^ 1;

    // issue next-chunk loads FIRST (drained at the LDS write below)
    const int kn = ((it + 1) << 5) & 511;
    LOADAB(kn);

    bf16x8 bfr[4];
#pragma unroll
    for (int nf = 0; nf < 4; ++nf)
      bfr[nf] = *(const bf16x8*)&u.s.B[cur][wn + nf * 16 + ln][quad * 8];
#pragma unroll
    for (int mf = 0; mf < 4; ++mf) {
      bf16x8 af = *(const bf16x8*)&u.s.A[cur][wm + mf * 16 + ln][quad * 8];
#pragma unroll
      for (int nf = 0; nf < 4; ++nf)
        acc[mf][nf] = __builtin_amdgcn_mfma_f32_16x16x32_bf16(af, bfr[nf], acc[mf][nf], 0, 0, 0);
    }

    if (it + 1 < 16) {
      *(bf16x8*)&u.s.A[nxt][strow][stcol] = a0;
      *(bf16x8*)&u.s.A[nxt][64 + strow][stcol] = a1;
      *(bf16x8*)&u.s.B[nxt][strow][stcol] = b0;
      *(bf16x8*)&u.s.B[nxt][64 + strow][stcol] = b1;
      __syncthreads();
    }
  }
#undef LOADAB

  // ---------------- epilogue (C layout: col=lane&15, row=quad*4+reg) ----------
  if (MODE == 0 && nt >= 8) {
    // V: LDS transpose -> coalesced V^T rows. Tile = 128 s x 128 d-cols.
    const int bb = mt >> 4, sq0 = (mt & 15) * 128;
#pragma unroll
    for (int half = 0; half < 2; ++half) {
      __syncthreads();  // A/B buffers dead; T aliases them
      if ((w & 1) == half) {
#pragma unroll
        for (int nf = 0; nf < 4; ++nf) {
          const float bv = bias[nt * 128 + half * 64 + nf * 16 + ln];
#pragma unroll
          for (int mf = 0; mf < 4; ++mf)
#pragma unroll
            for (int r = 0; r < 4; ++r)
              u.T[nf * 16 + ln][wm + mf * 16 + quad * 4 + r] = f2h(acc[mf][nf][r] + bv);
        }
      }
      __syncthreads();
#pragma unroll
      for (int rep = 0; rep < 4; ++rep) {
        const int row = rep * 16 + (t >> 4), c = t & 15;
        const bf16x8 val = *(const bf16x8*)&u.T[row][c * 8];
        const int hd = (nt - 8) * 128 + half * 64 + row;
        const int hh = hd >> 6, dd = hd & 63;
        *(bf16x8*)(v_out + ((size_t)(bb * 8 + hh) * 64 + dd) * 2048 + sq0 + c * 8) = val;
      }
    }
    return;
  }

#pragma unroll
  for (int mf = 0; mf < 4; ++mf) {
    const int m = mt * 128 + wm + mf * 16 + quad * 4;
#pragma unroll
    for (int nf = 0; nf < 4; ++nf) {
      const int n = nt * 128 + wn + nf * 16 + ln;
      const float bv = bias[n];
      if (MODE == 0) {
        const int hd = n & 511;
        const int hh = hd >> 6, dd = hd & 63;
        const int bb = m >> 11, sq = m & 2047;
        if (n < 512) {
#pragma unroll
          for (int r = 0; r < 4; ++r)
            q_out[((size_t)(bb * 8 + hh) * 2048 + sq + r) * 64 + dd] =
                f2bf((acc[mf][nf][r] + bv) * QSCALE);
        } else {
#pragma unroll
          for (int r = 0; r < 4; ++r)
            k_out[((size_t)(bb * 8 + hh) * 2048 + sq + r) * 64 + dd] = f2bf(acc[mf][nf][r] + bv);
        }
      } else {
#pragma unroll
        for (int r = 0; r < 4; ++r) f_out[(size_t)(m + r) * 512 + n] = acc[mf][nf][r] + bv;
      }
    }
  }
}

// ---------------- fused flash attention, S^T orientation, dbuf, K=32 PV -----
// grid 512: bh = blk&31, qt = blk>>5. 4 waves x 32 q-rows, BN=64.
// Permuted key mapping: QK^T K-frag (h,e) loads K_lds row h*32+kperm+e*4, so
// C rows hold keys h*32+quad*8+e*4+r (16x16x32 f16 A-slot order). Masks use
// the ballot-natural layout [b][it][q][4]: bit for key 64g+32h+8quad+4e+r is
// bit (16(g&1)+8h+e) of (half(g>=2) of W_r) >> 2quad. kt loop = 8 superblocks
// x 4 (dbuf parity compile-time). QK C-operand = hoisted zero. setprio on MFMA.
__global__ __launch_bounds__(256, 2) void attn_k(const unsigned short* __restrict__ Qg,
                                                 const unsigned short* __restrict__ Kg,
                                                 const unsigned short* __restrict__ Vg,
                                                 const unsigned long long* __restrict__ Mg,
                                                 unsigned short* __restrict__ Og) {
  __shared__ unsigned short K_lds[2][64][64];  // [buf][key][d] bf16, chunk-swizzled
  __shared__ unsigned short V_lds[2][64][64];  // [buf][d][key] f16, chunk-swizzled

  const int t = threadIdx.x;
  const int w = t >> 6, lane = t & 63, ln = lane & 15, quad = lane >> 4;
  const int bh = blockIdx.x & 31, qt = blockIdx.x >> 5, bb = bh >> 3;
  const int sbase = qt * 128;

  const unsigned short* Qp = Qg + (size_t)bh * (2048 * 64);
  const unsigned short* Kp = Kg + (size_t)bh * (2048 * 64);
  const unsigned short* Vp = Vg + (size_t)bh * (64 * 2048);
  // mask base: [b][it(8)][q(2048)][4]; this thread's q-row = sbase+w*32+ln
  const unsigned long long* Mb = Mg + ((size_t)bb * 8 * 2048 + sbase + w * 32 + ln) * 4;

  bf16x8 qf[2][2];
#pragma unroll
  for (int qg = 0; qg < 2; ++qg) {
    const int qrow = sbase + w * 32 + qg * 16 + ln;
    qf[qg][0] = *(const bf16x8*)(Qp + (size_t)qrow * 64 + quad * 8);
    qf[qg][1] = *(const bf16x8*)(Qp + (size_t)qrow * 64 + 32 + quad * 8);
  }

  // ones B-frag (K=32): B[k][n]=1 iff n==0 -> lane ln==0 holds 8 ones
  const _Float16 one_h = (_Float16)((ln == 0) ? 1.0f : 0.0f);
  const f16x8 vf_one = (f16x8){one_h, one_h, one_h, one_h, one_h, one_h, one_h, one_h};

  const f32x4 zf = (f32x4){0.f, 0.f, 0.f, 0.f};  // hoisted zero C-operand

  f32x4 acc_o[2][4];
#pragma unroll
  for (int qg = 0; qg < 2; ++qg)
#pragma unroll
    for (int dg = 0; dg < 4; ++dg) acc_o[qg][dg] = zf;
  f32x4 acc_1[2] = {zf, zf};

  const int strow = t >> 2;
  const int stcol = (t & 3) * 16;       // global column base (ushorts)
  const int c0 = (t & 3) * 2;           // LDS chunk index (16B units), even
  const int gkw = (strow & 3) | (((strow >> 3) & 1) << 2);  // K write swizzle
  const int gvw = strow & 7;                                // V write swizzle

  // per-lane base pointers (linear; last-iter prefetch reads adjacent ws)
  const unsigned short* Kl = Kp + (size_t)strow * 64 + stcol;
  const unsigned short* Vl = Vp + (size_t)strow * 2048 + stcol;

  bf16x8 kr0 = *(const bf16x8*)(Kl);
  bf16x8 kr1 = *(const bf16x8*)(Kl + 8);
  bf16x8 vr0 = *(const bf16x8*)(Vl);
  bf16x8 vr1 = *(const bf16x8*)(Vl + 8);
  *(bf16x8*)&K_lds[0][strow][(c0 ^ gkw) << 3] = kr0;
  *(bf16x8*)&K_lds[0][strow][((c0 + 1) ^ gkw) << 3] = kr1;
  *(bf16x8*)&V_lds[0][strow][(c0 ^ gvw) << 3] = vr0;
  *(bf16x8*)&V_lds[0][strow][((c0 + 1) ^ gvw) << 3] = vr1;
  // masks superblock 0 (per qg: words W0,W1 | W2,W3)
  u64x2 Wlo[2], Whi[2];
#pragma unroll
  for (int qg = 0; qg < 2; ++qg) {
    Wlo[qg] = *(const u64x2*)(Mb + qg * 64);
    Whi[qg] = *(const u64x2*)(Mb + qg * 64 + 2);
  }
  __syncthreads();

  const int kperm = ((ln >> 2) << 3) + (ln & 3);             // permuted K row base
  const int gkr = (ln & 3) | (((ln >> 2) & 1) << 2);         // = K swizzle of krow
  const int gvr = ln & 7;                                    // = V swizzle of vrow
  const int kc = (quad ^ gkr) << 3;                          // phys col of chunk `quad`
  const unsigned q2 = quad << 1;                             // mask pre-shift

  for (int kts = 0; kts < 8; ++kts) {
    // prefetch next superblock's masks (wraps to it=0 at the end; unused)
    const size_t itn = (size_t)((kts < 7) ? kts + 1 : 0) * 8192;
    u64x2 nWlo[2], nWhi[2];
#pragma unroll
    for (int qg = 0; qg < 2; ++qg) {
      nWlo[qg] = *(const u64x2*)(Mb + itn + qg * 64);
      nWhi[qg] = *(const u64x2*)(Mb + itn + qg * 64 + 2);
    }

#pragma unroll
    for (int j = 0; j < 4; ++j) {
      const int kt = kts * 4 + j;
      const int cur = j & 1, nxt = cur ^ 1;  // (kts*4+j)&1 == j&1

      // next-tile global prefetch (drained at LDS writes below)
      kr0 = *(const bf16x8*)(Kl + (size_t)(kt + 1) * 4096);
      kr1 = *(const bf16x8*)(Kl + (size_t)(kt + 1) * 4096 + 8);
      vr0 = *(const bf16x8*)(Vl + (kt + 1) * 64);
      vr1 = *(const bf16x8*)(Vl + (kt + 1) * 64 + 8);

      // S^T with permuted key rows: frag f=h*2+e covers keys h*32+quad*8+e*4+r
      f32x4 sc[2][4];
      __builtin_amdgcn_s_setprio(1);
#pragma unroll
      for (int h = 0; h < 2; ++h)
#pragma unroll
        for (int e = 0; e < 2; ++e) {
          const int krow = h * 32 + kperm + e * 4;
          bf16x8 kf0 = *(const bf16x8*)&K_lds[cur][krow][kc];
          bf16x8 kf1 = *(const bf16x8*)&K_lds[cur][krow][kc ^ 32];  // chunk quad+4
#pragma unroll
          for (int qg = 0; qg < 2; ++qg) {
            f32x4 z = __builtin_amdgcn_mfma_f32_16x16x32_bf16(kf0, qf[qg][0], zf, 0, 0, 0);
            sc[qg][h * 2 + e] = __builtin_amdgcn_mfma_f32_16x16x32_bf16(kf1, qf[qg][1], z, 0, 0, 0);
          }
        }
      __builtin_amdgcn_s_setprio(0);

      // hoist V-frags (b128): B[k=quad*8+j][n=d] = V_lds[d][h*32+quad*8]
      f16x8 vfa[2][4];
#pragma unroll
      for (int h = 0; h < 2; ++h)
#pragma unroll
        for (int dg = 0; dg < 4; ++dg)
          vfa[h][dg] = *(const f16x8*)&V_lds[cur][dg * 16 + ln][((h * 4 + quad) ^ gvr) << 3];

      // mask decode (ballot-natural layout) + exp2 -> P, packed cvt
      f16x8 pa[2][2];
#pragma unroll
      for (int qg = 0; qg < 2; ++qg) {
        const unsigned s0 = (unsigned)(Wlo[qg][0] >> (j >= 2 ? 32 : 0)) >> q2;
        const unsigned s1 = (unsigned)(Wlo[qg][1] >> (j >= 2 ? 32 : 0)) >> q2;
        const unsigned s2 = (unsigned)(Whi[qg][0] >> (j >= 2 ? 32 : 0)) >> q2;
        const unsigned s3 = (unsigned)(Whi[qg][1] >> (j >= 2 ? 32 : 0)) >> q2;
#pragma unroll
        for (int h = 0; h < 2; ++h) {
          float p[8];
#pragma unroll
          for (int e = 0; e < 2; ++e) {
            const int pos = (j & 1) * 16 + h * 8 + e;
            p[e * 4 + 0] =
                EXP2F(__int_as_float(__float_as_int(sc[qg][h * 2 + e][0]) & sbit(s0, pos)));
            p[e * 4 + 1] =
                EXP2F(__int_as_float(__float_as_int(sc[qg][h * 2 + e][1]) & sbit(s1, pos)));
            p[e * 4 + 2] =
                EXP2F(__int_as_float(__float_as_int(sc[qg][h * 2 + e][2]) & sbit(s2, pos)));
            p[e * 4 + 3] =
                EXP2F(__int_as_float(__float_as_int(sc[qg][h * 2 + e][3]) & sbit(s3, pos)));
          }
          pa[qg][h] = pk8(p);
        }
      }

      // O += P @ V (K=32) ; lsum += P @ ones (col 0 of acc_1)
      __builtin_amdgcn_s_setprio(1);
#pragma unroll
      for (int h = 0; h < 2; ++h)
#pragma unroll
        for (int qg = 0; qg < 2; ++qg) {
#pragma unroll
          for (int dg = 0; dg < 4; ++dg)
            acc_o[qg][dg] = mfma_pv(pa[qg][h], vfa[h][dg], acc_o[qg][dg]);
          acc_1[qg] = mfma_pv(pa[qg][h], vf_one, acc_1[qg]);
        }
      __builtin_amdgcn_s_setprio(0);

      if (kt < 31) {
        *(bf16x8*)&K_lds[nxt][strow][(c0 ^ gkw) << 3] = kr0;
        *(bf16x8*)&K_lds[nxt][strow][((c0 + 1) ^ gkw) << 3] = kr1;
        *(bf16x8*)&V_lds[nxt][strow][(c0 ^ gvw) << 3] = vr0;
        *(bf16x8*)&V_lds[nxt][strow][((c0 + 1) ^ gvw) << 3] = vr1;
        __syncthreads();
      }
    }
    Wlo[0] = nWlo[0]; Wlo[1] = nWlo[1];
    Whi[0] = nWhi[0]; Whi[1] = nWhi[1];
  }

  // epilogue: lsum for row q=quad*4+r lives in acc_1[qg][r] at lanes ln==0
  unsigned short* Op = Og + (size_t)bb * 2048 * 512 + (size_t)(bh & 7) * 64;
#pragma unroll
  for (int qg = 0; qg < 2; ++qg)
#pragma unroll
    for (int r = 0; r < 4; ++r) {
      const float inv = 1.0f / __shfl(acc_1[qg][r], quad * 16);
      const int sq = sbase + w * 32 + qg * 16 + quad * 4 + r;
#pragma unroll
      for (int dg = 0; dg < 4; ++dg)
        Op[(size_t)sq * 512 + dg * 16 + ln] = f2bf(acc_o[qg][dg][r] * inv);
    }
}

// ---------------------------------------------------------------------------
extern "C" void kernel_launch(void* const* d_in, const int* in_sizes, int n_in, void* d_out,
                              int out_size, void* d_ws, size_t ws_size, hipStream_t stream) {
  const float* x = (const float*)d_in[0];
  const float* adj = (const float*)d_in[1];
  const float* wqkv = (const float*)d_in[2];
  const float* bqkv = (const float*)d_in[3];
  const float* outw = (const float*)d_in[4];
  const float* outb = (const float*)d_in[5];
  float* out = (float*)d_out;

  char* ws = (char*)d_ws;
  unsigned long long* abits = (unsigned long long*)(ws + 10485760);  //  2.0 MB [b][it][q][4]
  unsigned short* Qb = (unsigned short*)(ws + 27262976);             //  8.0 MB (b,h,s,d) bf16
  unsigned short* Kb = (unsigned short*)(ws + 35651584);             //  8.0 MB (b,h,s,d) bf16
  unsigned short* Vb = (unsigned short*)(ws + 44040192);             //  8.0 MB (b,h,d,s) f16
  unsigned short* Ob = (unsigned short*)(ws + 52428800);             //  8.0 MB (b,s,e) bf16

  // blocks [0,512): adj bit-pack; blocks [512,1280): QKV gemm
  gemm128_k<0><<<1280, 256, 0, stream>>>(x, nullptr, wqkv, bqkv, 12, Qb, Kb, Vb, nullptr,
                                         adj, abits);

  attn_k<<<512, 256, 0, stream>>>(Qb, Kb, Vb, abits, Ob);

  gemm128_k<1><<<256, 256, 0, stream>>>(nullptr, Ob, outw, outb, 4, nullptr, nullptr, nullptr,
                                        out, nullptr, nullptr);
}

// Round 10
// 199.627 us; speedup vs baseline: 1.0896x; 1.0896x over previous
//
#include <hip/hip_runtime.h>

// ---------------------------------------------------------------------------
// MultiHeadAttention: x(4,2048,512) fp32, adj(4,2048,2048) 0/1 fp32
// R21: R19 pipeline (best: 203.3us) + gemm1 retile. gemm1 was 256 blocks on
// 256 CUs = 1 block/CU = 1 wave/SIMD (the R13 anti-pattern): every K-iter's
// vmcnt->ds_write->barrier chain fully exposed despite a 1.8us MFMA floor.
// New gemm64_k: 128x64 tiles -> 512 blocks -> 2 blocks/CU, 8 MFMA/iter,
// acc[4][2], B-LDS 64 rows (30KB total). prep/gemm0/attn identical to R19
// (attn 49.7us, 0 bank conflicts; R20's fusion experiment reverted — adj
// streaming co-resident with MFMA blocks thrashes L2 and starves both).
// ---------------------------------------------------------------------------

typedef __attribute__((ext_vector_type(8))) short bf16x8;
typedef __attribute__((ext_vector_type(4))) float f32x4;
typedef __attribute__((ext_vector_type(4))) unsigned short ushort4v;
typedef __attribute__((ext_vector_type(4))) _Float16 f16x4;
typedef __attribute__((ext_vector_type(8))) _Float16 f16x8;
typedef __attribute__((ext_vector_type(2))) __fp16 h16x2;  // cvt_pkrtz return type
typedef __attribute__((ext_vector_type(2))) unsigned long long u64x2;

#if __has_builtin(__builtin_amdgcn_exp2f)
#define EXP2F(x) __builtin_amdgcn_exp2f(x)
#else
#define EXP2F(x) exp2f(x)
#endif

// 0.125 (1/sqrt(64)) * log2(e), folded into Q at the QKV-gemm epilogue
#define QSCALE 0.18033688011112042f

__device__ __forceinline__ unsigned short f2bf(float f) {
  unsigned int u = __float_as_uint(f);
  u += 0x7FFFu + ((u >> 16) & 1u);
  return (unsigned short)(u >> 16);
}
__device__ __forceinline__ unsigned short f2h(float f) {
  union { _Float16 h; unsigned short u; } cv;
  cv.h = (_Float16)f;
  return cv.u;
}

// sign-extend bit (pos) of w to 0 / 0xFFFFFFFF
__device__ __forceinline__ int sbit(unsigned w, int pos) {
  return ((int)(w << (31 - pos))) >> 31;  // compiler emits v_bfe_i32
}

// pack 8 floats -> f16x8 via 4 packed RTZ converts
__device__ __forceinline__ f16x8 pk8(const float* p) {
  union { struct { h16x2 a, b, c, d; } s; f16x8 v; } u;
  u.s.a = __builtin_amdgcn_cvt_pkrtz(p[0], p[1]);
  u.s.b = __builtin_amdgcn_cvt_pkrtz(p[2], p[3]);
  u.s.c = __builtin_amdgcn_cvt_pkrtz(p[4], p[5]);
  u.s.d = __builtin_amdgcn_cvt_pkrtz(p[6], p[7]);
  return u.v;
}

// PV matmul: K=32 f16 (slot pairing identical in A and B, so a two-K=16
// fallback is mathematically identical if the builtin is absent)
__device__ __forceinline__ f32x4 mfma_pv(f16x8 a, f16x8 b, f32x4 c) {
#if __has_builtin(__builtin_amdgcn_mfma_f32_16x16x32_f16)
  return __builtin_amdgcn_mfma_f32_16x16x32_f16(a, b, c, 0, 0, 0);
#else
  union { f16x8 v; struct { f16x4 lo, hi; } s; } ua, ub;
  ua.v = a; ub.v = b;
  c = __builtin_amdgcn_mfma_f32_16x16x16f16(ua.s.lo, ub.s.lo, c, 0, 0, 0);
  return __builtin_amdgcn_mfma_f32_16x16x16f16(ua.s.hi, ub.s.hi, c, 0, 0, 0);
#endif
}

// ---------------- fused prep: casts + adj bit-pack, one launch ---------------
__global__ __launch_bounds__(256) void prep_k(const float* __restrict__ x,
                                              unsigned short* __restrict__ x_bf,
                                              const float* __restrict__ wqkv,
                                              unsigned short* __restrict__ wqkv_bf,
                                              const float* __restrict__ outw,
                                              unsigned short* __restrict__ outw_bf,
                                              const float* __restrict__ adj,
                                              unsigned long long* __restrict__ abits) {
  const int bid = blockIdx.x;
  if (bid < 5120) {
    const float* in; unsigned short* out; int i;
    if (bid < 4096) { in = x; out = x_bf; i = bid * 256 + threadIdx.x; }
    else if (bid < 4864) { in = wqkv; out = wqkv_bf; i = (bid - 4096) * 256 + threadIdx.x; }
    else { in = outw; out = outw_bf; i = (bid - 4864) * 256 + threadIdx.x; }
    float4 v = ((const float4*)in)[i];
    ushort4v o;
    o[0] = f2bf(v.x); o[1] = f2bf(v.y); o[2] = f2bf(v.z); o[3] = f2bf(v.w);
    ((ushort4v*)out)[i] = o;
  } else {
    // adj -> ballot-natural masks: [b][it(8)][q][4]; W_c bit l = adj[q][256it+4l+c]
    const int gw = (bid - 5120) * 4 + (threadIdx.x >> 6);  // 0..8191 = b*2048+q
    const int l = threadIdx.x & 63;
    const int b = gw >> 11, q = gw & 2047;
    const float4* row = (const float4*)(adj + ((size_t)b * 2048 + q) * 2048) + l;
    unsigned long long* ob = abits + ((size_t)b * 8 * 2048 + q) * 4;
#pragma unroll
    for (int it = 0; it < 8; ++it) {
      const float4 v = row[(size_t)it * 64];
      const unsigned long long w0 = __ballot(v.x != 0.f);
      const unsigned long long w1 = __ballot(v.y != 0.f);
      const unsigned long long w2 = __ballot(v.z != 0.f);
      const unsigned long long w3 = __ballot(v.w != 0.f);
      if (l == 0) {
        ob[(size_t)it * 8192 + 0] = w0;
        ob[(size_t)it * 8192 + 1] = w1;
        ob[(size_t)it * 8192 + 2] = w2;
        ob[(size_t)it * 8192 + 3] = w3;
      }
    }
  }
}

// ---------------- 128x128 bf16 MFMA GEMM (MODE0: QKV projection) -------------
// XCD-local tiling: blk&7 = XCD. Double-buffered LDS, one barrier/iter.
// Epilogue: Q scaled bf16 / K bf16 / V f16 LDS-transposed.
__global__ __launch_bounds__(256, 3) void gemm128_k(const unsigned short* __restrict__ A,
                                                    const unsigned short* __restrict__ Bt,
                                                    const float* __restrict__ bias, int Kdim,
                                                    int Ntiles, unsigned short* __restrict__ q_out,
                                                    unsigned short* __restrict__ k_out,
                                                    unsigned short* __restrict__ v_out) {
  __shared__ union {
    struct { unsigned short A[2][128][40], B[2][128][40]; } s;  // 40 KB
    unsigned short T[64][136];                                  // V-transpose staging
  } u;

  const int t = threadIdx.x;
  const int lane = t & 63, w = t >> 6, ln = lane & 15, quad = lane >> 4;
  const int xcd = blockIdx.x & 7, loc = blockIdx.x >> 3;
  const int mt = xcd * ((gridDim.x >> 3) / Ntiles) + loc / Ntiles;
  const int nt = loc % Ntiles;
  const int wm = (w >> 1) * 64, wn = (w & 1) * 64;
  const int strow = t >> 2, stcol = (t & 3) * 8;

  const size_t abase = (size_t)(mt * 128 + strow) * Kdim + stcol;
  const size_t bbase = (size_t)(nt * 128 + strow) * Kdim + stcol;

  f32x4 acc[4][4];
#pragma unroll
  for (int i = 0; i < 4; ++i)
#pragma unroll
    for (int j = 0; j < 4; ++j) acc[i][j] = (f32x4){0.f, 0.f, 0.f, 0.f};

  // prologue: load + stage chunk 0 into buf 0
  bf16x8 a0 = *(const bf16x8*)(A + abase);
  bf16x8 a1 = *(const bf16x8*)(A + abase + (size_t)64 * Kdim);
  bf16x8 b0 = *(const bf16x8*)(Bt + bbase);
  bf16x8 b1 = *(const bf16x8*)(Bt + bbase + (size_t)64 * Kdim);
  *(bf16x8*)&u.s.A[0][strow][stcol] = a0;
  *(bf16x8*)&u.s.A[0][64 + strow][stcol] = a1;
  *(bf16x8*)&u.s.B[0][strow][stcol] = b0;
  *(bf16x8*)&u.s.B[0][64 + strow][stcol] = b1;
  __syncthreads();

  const int iters = Kdim >> 5;
  for (int it = 0; it < iters; ++it) {
    const int cur = it & 1, nxt = cur ^ 1;

    const int kn = ((it + 1) << 5) & (Kdim - 1);
    a0 = *(const bf16x8*)(A + abase + kn);
    a1 = *(const bf16x8*)(A + abase + (size_t)64 * Kdim + kn);
    b0 = *(const bf16x8*)(Bt + bbase + kn);
    b1 = *(const bf16x8*)(Bt + bbase + (size_t)64 * Kdim + kn);

    bf16x8 bfr[4];
#pragma unroll
    for (int nf = 0; nf < 4; ++nf)
      bfr[nf] = *(const bf16x8*)&u.s.B[cur][wn + nf * 16 + ln][quad * 8];
#pragma unroll
    for (int mf = 0; mf < 4; ++mf) {
      bf16x8 af = *(const bf16x8*)&u.s.A[cur][wm + mf * 16 + ln][quad * 8];
#pragma unroll
      for (int nf = 0; nf < 4; ++nf)
        acc[mf][nf] = __builtin_amdgcn_mfma_f32_16x16x32_bf16(af, bfr[nf], acc[mf][nf], 0, 0, 0);
    }

    if (it + 1 < iters) {
      *(bf16x8*)&u.s.A[nxt][strow][stcol] = a0;
      *(bf16x8*)&u.s.A[nxt][64 + strow][stcol] = a1;
      *(bf16x8*)&u.s.B[nxt][strow][stcol] = b0;
      *(bf16x8*)&u.s.B[nxt][64 + strow][stcol] = b1;
      __syncthreads();
    }
  }

  // ---------------- epilogue (C layout: col=lane&15, row=quad*4+reg) ----------
  if (nt >= 8) {
    // V: LDS transpose -> coalesced V^T rows. Tile = 128 s x 128 d-cols.
    const int bb = mt >> 4, sq0 = (mt & 15) * 128;
#pragma unroll
    for (int half = 0; half < 2; ++half) {
      __syncthreads();  // A/B buffers dead; T aliases them
      if ((w & 1) == half) {
#pragma unroll
        for (int nf = 0; nf < 4; ++nf) {
          const float bv = bias[nt * 128 + half * 64 + nf * 16 + ln];
#pragma unroll
          for (int mf = 0; mf < 4; ++mf)
#pragma unroll
            for (int r = 0; r < 4; ++r)
              u.T[nf * 16 + ln][wm + mf * 16 + quad * 4 + r] = f2h(acc[mf][nf][r] + bv);
        }
      }
      __syncthreads();
#pragma unroll
      for (int rep = 0; rep < 4; ++rep) {
        const int row = rep * 16 + (t >> 4), c = t & 15;
        const bf16x8 val = *(const bf16x8*)&u.T[row][c * 8];
        const int hd = (nt - 8) * 128 + half * 64 + row;
        const int hh = hd >> 6, dd = hd & 63;
        *(bf16x8*)(v_out + ((size_t)(bb * 8 + hh) * 64 + dd) * 2048 + sq0 + c * 8) = val;
      }
    }
    return;
  }

#pragma unroll
  for (int mf = 0; mf < 4; ++mf) {
    const int m = mt * 128 + wm + mf * 16 + quad * 4;
#pragma unroll
    for (int nf = 0; nf < 4; ++nf) {
      const int n = nt * 128 + wn + nf * 16 + ln;
      const float bv = bias[n];
      const int hd = n & 511;
      const int hh = hd >> 6, dd = hd & 63;
      const int bb = m >> 11, sq = m & 2047;
      if (n < 512) {
#pragma unroll
        for (int r = 0; r < 4; ++r)
          q_out[((size_t)(bb * 8 + hh) * 2048 + sq + r) * 64 + dd] =
              f2bf((acc[mf][nf][r] + bv) * QSCALE);
      } else {
#pragma unroll
        for (int r = 0; r < 4; ++r)
          k_out[((size_t)(bb * 8 + hh) * 2048 + sq + r) * 64 + dd] = f2bf(acc[mf][nf][r] + bv);
      }
    }
  }
}

// ---------------- 128x64 bf16 MFMA GEMM (gemm1: out-proj, fp32+bias) ---------
// 512 blocks (64 mt x 8 nt) -> 2 blocks/CU: two independent waves per SIMD
// overlap the per-iter barrier chains (old 256-block version was 1 wave/SIMD
// = R13 anti-pattern, fully exposed latency for a 1.8us-of-MFMA job).
__global__ __launch_bounds__(256, 3) void gemm64_k(const unsigned short* __restrict__ A,
                                                   const unsigned short* __restrict__ Bt,
                                                   const float* __restrict__ bias,
                                                   float* __restrict__ f_out) {
  __shared__ struct { unsigned short A[2][128][40], B[2][64][40]; } s;  // 30 KB

  const int t = threadIdx.x;
  const int lane = t & 63, w = t >> 6, ln = lane & 15, quad = lane >> 4;
  const int xcd = blockIdx.x & 7, loc = blockIdx.x >> 3;  // loc 0..63
  const int mt = xcd * 8 + (loc >> 3);                    // 0..63
  const int nt = loc & 7;                                 // 0..7
  const int wm = (w >> 1) * 64, wn = (w & 1) * 32;
  const int strow = t >> 2, stcol = (t & 3) * 8;

  const size_t abase = (size_t)(mt * 128 + strow) * 512 + stcol;
  const size_t bbase = (size_t)(nt * 64 + strow) * 512 + stcol;

  f32x4 acc[4][2];
#pragma unroll
  for (int i = 0; i < 4; ++i)
#pragma unroll
    for (int j = 0; j < 2; ++j) acc[i][j] = (f32x4){0.f, 0.f, 0.f, 0.f};

  bf16x8 a0 = *(const bf16x8*)(A + abase);
  bf16x8 a1 = *(const bf16x8*)(A + abase + (size_t)64 * 512);
  bf16x8 b0 = *(const bf16x8*)(Bt + bbase);
  *(bf16x8*)&s.A[0][strow][stcol] = a0;
  *(bf16x8*)&s.A[0][64 + strow][stcol] = a1;
  *(bf16x8*)&s.B[0][strow][stcol] = b0;
  __syncthreads();

  for (int it = 0; it < 16; ++it) {
    const int cur = it & 1, nxt = cur ^ 1;

    const int kn = ((it + 1) << 5) & 511;
    a0 = *(const bf16x8*)(A + abase + kn);
    a1 = *(const bf16x8*)(A + abase + (size_t)64 * 512 + kn);
    b0 = *(const bf16x8*)(Bt + bbase + kn);

    bf16x8 bfr[2];
#pragma unroll
    for (int nf = 0; nf < 2; ++nf)
      bfr[nf] = *(const bf16x8*)&s.B[cur][wn + nf * 16 + ln][quad * 8];
#pragma unroll
    for (int mf = 0; mf < 4; ++mf) {
      bf16x8 af = *(const bf16x8*)&s.A[cur][wm + mf * 16 + ln][quad * 8];
#pragma unroll
      for (int nf = 0; nf < 2; ++nf)
        acc[mf][nf] = __builtin_amdgcn_mfma_f32_16x16x32_bf16(af, bfr[nf], acc[mf][nf], 0, 0, 0);
    }

    if (it + 1 < 16) {
      *(bf16x8*)&s.A[nxt][strow][stcol] = a0;
      *(bf16x8*)&s.A[nxt][64 + strow][stcol] = a1;
      *(bf16x8*)&s.B[nxt][strow][stcol] = b0;
      __syncthreads();
    }
  }

  // epilogue (C layout: col=lane&15, row=quad*4+reg)
#pragma unroll
  for (int mf = 0; mf < 4; ++mf) {
    const int m = mt * 128 + wm + mf * 16 + quad * 4;
#pragma unroll
    for (int nf = 0; nf < 2; ++nf) {
      const int n = nt * 64 + wn + nf * 16 + ln;
      const float bv = bias[n];
#pragma unroll
      for (int r = 0; r < 4; ++r) f_out[(size_t)(m + r) * 512 + n] = acc[mf][nf][r] + bv;
    }
  }
}

// ---------------- fused flash attention, S^T orientation, dbuf, K=32 PV -----
// grid 512: bh = blk&31, qt = blk>>5. 4 waves x 32 q-rows, BN=64.
// Permuted key mapping: QK^T K-frag (h,e) loads K_lds row h*32+kperm+e*4, so
// C rows hold keys h*32+quad*8+e*4+r (16x16x32 f16 A-slot order). Masks use
// the ballot-natural layout [b][it][q][4]: bit for key 64g+32h+8quad+4e+r is
// bit (16(g&1)+8h+e) of (half(g>=2) of W_r) >> 2quad. kt loop = 8 superblocks
// x 4 (dbuf parity compile-time). QK C-operand = hoisted zero. setprio on MFMA.
__global__ __launch_bounds__(256, 2) void attn_k(const unsigned short* __restrict__ Qg,
                                                 const unsigned short* __restrict__ Kg,
                                                 const unsigned short* __restrict__ Vg,
                                                 const unsigned long long* __restrict__ Mg,
                                                 unsigned short* __restrict__ Og) {
  __shared__ unsigned short K_lds[2][64][64];  // [buf][key][d] bf16, chunk-swizzled
  __shared__ unsigned short V_lds[2][64][64];  // [buf][d][key] f16, chunk-swizzled

  const int t = threadIdx.x;
  const int w = t >> 6, lane = t & 63, ln = lane & 15, quad = lane >> 4;
  const int bh = blockIdx.x & 31, qt = blockIdx.x >> 5, bb = bh >> 3;
  const int sbase = qt * 128;

  const unsigned short* Qp = Qg + (size_t)bh * (2048 * 64);
  const unsigned short* Kp = Kg + (size_t)bh * (2048 * 64);
  const unsigned short* Vp = Vg + (size_t)bh * (64 * 2048);
  // mask base: [b][it(8)][q(2048)][4]; this thread's q-row = sbase+w*32+ln
  const unsigned long long* Mb = Mg + ((size_t)bb * 8 * 2048 + sbase + w * 32 + ln) * 4;

  bf16x8 qf[2][2];
#pragma unroll
  for (int qg = 0; qg < 2; ++qg) {
    const int qrow = sbase + w * 32 + qg * 16 + ln;
    qf[qg][0] = *(const bf16x8*)(Qp + (size_t)qrow * 64 + quad * 8);
    qf[qg][1] = *(const bf16x8*)(Qp + (size_t)qrow * 64 + 32 + quad * 8);
  }

  // ones B-frag (K=32): B[k][n]=1 iff n==0 -> lane ln==0 holds 8 ones
  const _Float16 one_h = (_Float16)((ln == 0) ? 1.0f : 0.0f);
  const f16x8 vf_one = (f16x8){one_h, one_h, one_h, one_h, one_h, one_h, one_h, one_h};

  const f32x4 zf = (f32x4){0.f, 0.f, 0.f, 0.f};  // hoisted zero C-operand

  f32x4 acc_o[2][4];
#pragma unroll
  for (int qg = 0; qg < 2; ++qg)
#pragma unroll
    for (int dg = 0; dg < 4; ++dg) acc_o[qg][dg] = zf;
  f32x4 acc_1[2] = {zf, zf};

  const int strow = t >> 2;
  const int stcol = (t & 3) * 16;       // global column base (ushorts)
  const int c0 = (t & 3) * 2;           // LDS chunk index (16B units), even
  const int gkw = (strow & 3) | (((strow >> 3) & 1) << 2);  // K write swizzle
  const int gvw = strow & 7;                                // V write swizzle

  // per-lane base pointers (linear; last-iter prefetch reads adjacent ws)
  const unsigned short* Kl = Kp + (size_t)strow * 64 + stcol;
  const unsigned short* Vl = Vp + (size_t)strow * 2048 + stcol;

  bf16x8 kr0 = *(const bf16x8*)(Kl);
  bf16x8 kr1 = *(const bf16x8*)(Kl + 8);
  bf16x8 vr0 = *(const bf16x8*)(Vl);
  bf16x8 vr1 = *(const bf16x8*)(Vl + 8);
  *(bf16x8*)&K_lds[0][strow][(c0 ^ gkw) << 3] = kr0;
  *(bf16x8*)&K_lds[0][strow][((c0 + 1) ^ gkw) << 3] = kr1;
  *(bf16x8*)&V_lds[0][strow][(c0 ^ gvw) << 3] = vr0;
  *(bf16x8*)&V_lds[0][strow][((c0 + 1) ^ gvw) << 3] = vr1;
  // masks superblock 0 (per qg: words W0,W1 | W2,W3)
  u64x2 Wlo[2], Whi[2];
#pragma unroll
  for (int qg = 0; qg < 2; ++qg) {
    Wlo[qg] = *(const u64x2*)(Mb + qg * 64);
    Whi[qg] = *(const u64x2*)(Mb + qg * 64 + 2);
  }
  __syncthreads();

  const int kperm = ((ln >> 2) << 3) + (ln & 3);             // permuted K row base
  const int gkr = (ln & 3) | (((ln >> 2) & 1) << 2);         // = K swizzle of krow
  const int gvr = ln & 7;                                    // = V swizzle of vrow
  const int kc = (quad ^ gkr) << 3;                          // phys col of chunk `quad`
  const unsigned q2 = quad << 1;                             // mask pre-shift

  for (int kts = 0; kts < 8; ++kts) {
    // prefetch next superblock's masks (wraps to it=0 at the end; unused)
    const size_t itn = (size_t)((kts < 7) ? kts + 1 : 0) * 8192;
    u64x2 nWlo[2], nWhi[2];
#pragma unroll
    for (int qg = 0; qg < 2; ++qg) {
      nWlo[qg] = *(const u64x2*)(Mb + itn + qg * 64);
      nWhi[qg] = *(const u64x2*)(Mb + itn + qg * 64 + 2);
    }

#pragma unroll
    for (int j = 0; j < 4; ++j) {
      const int kt = kts * 4 + j;
      const int cur = j & 1, nxt = cur ^ 1;  // (kts*4+j)&1 == j&1

      // next-tile global prefetch (drained at LDS writes below)
      kr0 = *(const bf16x8*)(Kl + (size_t)(kt + 1) * 4096);
      kr1 = *(const bf16x8*)(Kl + (size_t)(kt + 1) * 4096 + 8);
      vr0 = *(const bf16x8*)(Vl + (kt + 1) * 64);
      vr1 = *(const bf16x8*)(Vl + (kt + 1) * 64 + 8);

      // S^T with permuted key rows: frag f=h*2+e covers keys h*32+quad*8+e*4+r
      f32x4 sc[2][4];
      __builtin_amdgcn_s_setprio(1);
#pragma unroll
      for (int h = 0; h < 2; ++h)
#pragma unroll
        for (int e = 0; e < 2; ++e) {
          const int krow = h * 32 + kperm + e * 4;
          bf16x8 kf0 = *(const bf16x8*)&K_lds[cur][krow][kc];
          bf16x8 kf1 = *(const bf16x8*)&K_lds[cur][krow][kc ^ 32];  // chunk quad+4
#pragma unroll
          for (int qg = 0; qg < 2; ++qg) {
            f32x4 z = __builtin_amdgcn_mfma_f32_16x16x32_bf16(kf0, qf[qg][0], zf, 0, 0, 0);
            sc[qg][h * 2 + e] = __builtin_amdgcn_mfma_f32_16x16x32_bf16(kf1, qf[qg][1], z, 0, 0, 0);
          }
        }
      __builtin_amdgcn_s_setprio(0);

      // hoist V-frags (b128): B[k=quad*8+j][n=d] = V_lds[d][h*32+quad*8]
      f16x8 vfa[2][4];
#pragma unroll
      for (int h = 0; h < 2; ++h)
#pragma unroll
        for (int dg = 0; dg < 4; ++dg)
          vfa[h][dg] = *(const f16x8*)&V_lds[cur][dg * 16 + ln][((h * 4 + quad) ^ gvr) << 3];

      // mask decode (ballot-natural layout) + exp2 -> P, packed cvt
      f16x8 pa[2][2];
#pragma unroll
      for (int qg = 0; qg < 2; ++qg) {
        const unsigned s0 = (unsigned)(Wlo[qg][0] >> (j >= 2 ? 32 : 0)) >> q2;
        const unsigned s1 = (unsigned)(Wlo[qg][1] >> (j >= 2 ? 32 : 0)) >> q2;
        const unsigned s2 = (unsigned)(Whi[qg][0] >> (j >= 2 ? 32 : 0)) >> q2;
        const unsigned s3 = (unsigned)(Whi[qg][1] >> (j >= 2 ? 32 : 0)) >> q2;
#pragma unroll
        for (int h = 0; h < 2; ++h) {
          float p[8];
#pragma unroll
          for (int e = 0; e < 2; ++e) {
            const int pos = (j & 1) * 16 + h * 8 + e;
            p[e * 4 + 0] =
                EXP2F(__int_as_float(__float_as_int(sc[qg][h * 2 + e][0]) & sbit(s0, pos)));
            p[e * 4 + 1] =
                EXP2F(__int_as_float(__float_as_int(sc[qg][h * 2 + e][1]) & sbit(s1, pos)));
            p[e * 4 + 2] =
                EXP2F(__int_as_float(__float_as_int(sc[qg][h * 2 + e][2]) & sbit(s2, pos)));
            p[e * 4 + 3] =
                EXP2F(__int_as_float(__float_as_int(sc[qg][h * 2 + e][3]) & sbit(s3, pos)));
          }
          pa[qg][h] = pk8(p);
        }
      }

      // O += P @ V (K=32) ; lsum += P @ ones (col 0 of acc_1)
      __builtin_amdgcn_s_setprio(1);
#pragma unroll
      for (int h = 0; h < 2; ++h)
#pragma unroll
        for (int qg = 0; qg < 2; ++qg) {
#pragma unroll
          for (int dg = 0; dg < 4; ++dg)
            acc_o[qg][dg] = mfma_pv(pa[qg][h], vfa[h][dg], acc_o[qg][dg]);
          acc_1[qg] = mfma_pv(pa[qg][h], vf_one, acc_1[qg]);
        }
      __builtin_amdgcn_s_setprio(0);

      if (kt < 31) {
        *(bf16x8*)&K_lds[nxt][strow][(c0 ^ gkw) << 3] = kr0;
        *(bf16x8*)&K_lds[nxt][strow][((c0 + 1) ^ gkw) << 3] = kr1;
        *(bf16x8*)&V_lds[nxt][strow][(c0 ^ gvw) << 3] = vr0;
        *(bf16x8*)&V_lds[nxt][strow][((c0 + 1) ^ gvw) << 3] = vr1;
        __syncthreads();
      }
    }
    Wlo[0] = nWlo[0]; Wlo[1] = nWlo[1];
    Whi[0] = nWhi[0]; Whi[1] = nWhi[1];
  }

  // epilogue: lsum for row q=quad*4+r lives in acc_1[qg][r] at lanes ln==0
  unsigned short* Op = Og + (size_t)bb * 2048 * 512 + (size_t)(bh & 7) * 64;
#pragma unroll
  for (int qg = 0; qg < 2; ++qg)
#pragma unroll
    for (int r = 0; r < 4; ++r) {
      const float inv = 1.0f / __shfl(acc_1[qg][r], quad * 16);
      const int sq = sbase + w * 32 + qg * 16 + quad * 4 + r;
#pragma unroll
      for (int dg = 0; dg < 4; ++dg)
        Op[(size_t)sq * 512 + dg * 16 + ln] = f2bf(acc_o[qg][dg][r] * inv);
    }
}

// ---------------------------------------------------------------------------
extern "C" void kernel_launch(void* const* d_in, const int* in_sizes, int n_in, void* d_out,
                              int out_size, void* d_ws, size_t ws_size, hipStream_t stream) {
  const float* x = (const float*)d_in[0];
  const float* adj = (const float*)d_in[1];
  const float* wqkv = (const float*)d_in[2];
  const float* bqkv = (const float*)d_in[3];
  const float* outw = (const float*)d_in[4];
  const float* outb = (const float*)d_in[5];
  float* out = (float*)d_out;

  char* ws = (char*)d_ws;
  unsigned short* x_bf = (unsigned short*)(ws);                      //  8.0 MB
  unsigned short* wqkv_bf = (unsigned short*)(ws + 8388608);         //  1.5 MB
  unsigned short* outw_bf = (unsigned short*)(ws + 9961472);         //  0.5 MB
  unsigned long long* abits = (unsigned long long*)(ws + 10485760);  //  2.0 MB [b][it][q][4]
  unsigned short* Qb = (unsigned short*)(ws + 27262976);             //  8.0 MB (b,h,s,d) bf16
  unsigned short* Kb = (unsigned short*)(ws + 35651584);             //  8.0 MB (b,h,s,d) bf16
  unsigned short* Vb = (unsigned short*)(ws + 44040192);             //  8.0 MB (b,h,d,s) f16
  unsigned short* Ob = (unsigned short*)(ws + 52428800);             //  8.0 MB (b,s,e) bf16

  prep_k<<<7168, 256, 0, stream>>>(x, x_bf, wqkv, wqkv_bf, outw, outw_bf, adj, abits);

  gemm128_k<<<768, 256, 0, stream>>>(x_bf, wqkv_bf, bqkv, 512, 12, Qb, Kb, Vb);

  attn_k<<<512, 256, 0, stream>>>(Qb, Kb, Vb, abits, Ob);

  gemm64_k<<<512, 256, 0, stream>>>(Ob, outw_bf, outb, out);
}